// Round 3
// baseline (256.621 us; speedup 1.0000x reference)
//
#include <hip/hip_runtime.h>
#include <hip/hip_bf16.h>

// Problem constants (from reference)
#define BB 4
#define CC 64
#define NXX 432
#define NYY 496
#define GG (NXX * NYY)          // 214272 cells per batch
#define PP 80000                // total pillars (B * P_PER)

typedef float v4f __attribute__((ext_vector_type(4)));  // native vec for nontemporal builtin

// Reference reduces to a dense BEV scatter: prob_buf is zeros (kept bug) so
// p == 0 -> out = spatial. Output [B,C,NY,NX] = pillar_features scattered.

// Kernel 1: init cell->pillar map to -1 (d_ws is re-poisoned each call).
__global__ void k_init_map(int* __restrict__ map) {
    int i = blockIdx.x * blockDim.x + threadIdx.x;   // one int4 per thread
    const int n4 = (BB * GG) / 4;                    // 214272
    if (i < n4) {
        ((int4*)map)[i] = make_int4(-1, -1, -1, -1);
    }
}

// Kernel 2: scatter pillar ids into the map (coords unique per batch).
__global__ void k_scatter_ids(const int* __restrict__ coords, int* __restrict__ map) {
    int i = blockIdx.x * blockDim.x + threadIdx.x;
    if (i < PP) {
        int4 cd = ((const int4*)coords)[i];          // (b, z, y, x), z == 0
        int g = cd.x * GG + cd.y + cd.z * NXX + cd.w;
        map[g] = i;
    }
}

// Kernel 3: gather pass. One thread = 4 consecutive cells x ALL 64 channels.
// - map read once (int4 per thread)
// - pf loads UNCONDITIONAL from clamped pillar id (empty cells broadcast
//   pillar 0's row, L2-resident), selected to zero afterward -> all 64
//   dwordx4 loads are branch-free and pipelinable.
// - output via nontemporal stores (pure 219 MB stream; keep it out of L2 so
//   the random pf gathers keep their hit rate).
__global__ void k_gather(const float* __restrict__ pf,
                         const int* __restrict__ map,
                         float* __restrict__ out) {
    int t = blockIdx.x * blockDim.x + threadIdx.x;   // cell-group id (4 cells)
    const int nGroups = (BB * GG) / 4;               // 214272 (grid covers exactly)
    if (t >= nGroups) return;

    int cellBase = t * 4;
    int b = cellBase / GG;                           // G%4==0: group never crosses batch
    int cellInB = cellBase - b * GG;

    int4 pids = ((const int4*)map)[t];
    const v4f* pf4 = (const v4f*)pf;                 // pf rows: 64 floats = 16 vec4

    bool v0 = pids.x >= 0, v1 = pids.y >= 0, v2 = pids.z >= 0, v3 = pids.w >= 0;
    int i0 = (v0 ? pids.x : 0) * 16;
    int i1 = (v1 ? pids.y : 0) * 16;
    int i2 = (v2 ? pids.z : 0) * 16;
    int i3 = (v3 ? pids.w : 0) * 16;

    const v4f zero = (v4f)(0.f);
    float* outBase = out + (size_t)(b * CC) * GG + cellInB;  // 16B aligned

    #pragma unroll
    for (int cg = 0; cg < 16; ++cg) {                // channels 4*cg .. 4*cg+3
        v4f r0 = pf4[i0 + cg]; r0 = v0 ? r0 : zero;
        v4f r1 = pf4[i1 + cg]; r1 = v1 ? r1 : zero;
        v4f r2 = pf4[i2 + cg]; r2 = v2 ? r2 : zero;
        v4f r3 = pf4[i3 + cg]; r3 = v3 ? r3 : zero;

        // transpose: w_k = channel (4*cg+k) across the 4 cells
        v4f w0 = (v4f){r0.x, r1.x, r2.x, r3.x};
        v4f w1 = (v4f){r0.y, r1.y, r2.y, r3.y};
        v4f w2 = (v4f){r0.z, r1.z, r2.z, r3.z};
        v4f w3 = (v4f){r0.w, r1.w, r2.w, r3.w};

        __builtin_nontemporal_store(w0, (v4f*)(outBase + (size_t)(4 * cg + 0) * GG));
        __builtin_nontemporal_store(w1, (v4f*)(outBase + (size_t)(4 * cg + 1) * GG));
        __builtin_nontemporal_store(w2, (v4f*)(outBase + (size_t)(4 * cg + 2) * GG));
        __builtin_nontemporal_store(w3, (v4f*)(outBase + (size_t)(4 * cg + 3) * GG));
    }
}

extern "C" void kernel_launch(void* const* d_in, const int* in_sizes, int n_in,
                              void* d_out, int out_size, void* d_ws, size_t ws_size,
                              hipStream_t stream) {
    const float* pf     = (const float*)d_in[0];     // [80000, 64] f32
    const int*   coords = (const int*)d_in[7];       // [80000, 4] i32 (b,z,y,x)
    float*       out    = (float*)d_out;             // [B, C, NY, NX] f32
    int*         map    = (int*)d_ws;                // [B*G] i32 cell->pillar (3.43 MB)

    const int n4 = (BB * GG) / 4;                    // 214272
    k_init_map<<<dim3((n4 + 255) / 256), dim3(256), 0, stream>>>(map);
    k_scatter_ids<<<dim3((PP + 255) / 256), dim3(256), 0, stream>>>(coords, map);

    const int nGroups = (BB * GG) / 4;               // 214272 = 837 * 256 exactly
    k_gather<<<dim3((nGroups + 255) / 256), dim3(256), 0, stream>>>(pf, map, out);
}

// Round 4
// 249.930 us; speedup vs baseline: 1.0268x; 1.0268x over previous
//
#include <hip/hip_runtime.h>
#include <hip/hip_bf16.h>

// Problem constants (from reference)
#define BB 4
#define CC 64
#define NXX 432
#define NYY 496
#define GG (NXX * NYY)          // 214272 cells per batch
#define PP 80000                // total pillars (B * P_PER)

typedef float v4f __attribute__((ext_vector_type(4)));

// Reference reduces to a dense BEV scatter: prob_buf is zeros (kept bug) so
// p == 0 -> out = spatial. Output [B,C,NY,NX] = pillar_features scattered.

// Kernel 1: init cell->pillar map to -1.
__global__ void k_init_map(int* __restrict__ map) {
    int i = blockIdx.x * blockDim.x + threadIdx.x;   // one int4 per thread
    const int n4 = (BB * GG) / 4;                    // 214272
    if (i < n4) {
        ((int4*)map)[i] = make_int4(-1, -1, -1, -1);
    }
}

// Kernel 2: scatter pillar ids into the map (coords unique per batch).
__global__ void k_scatter_ids(const int* __restrict__ coords, int* __restrict__ map) {
    int i = blockIdx.x * blockDim.x + threadIdx.x;
    if (i < PP) {
        int4 cd = ((const int4*)coords)[i];          // (b, z, y, x), z == 0
        int g = cd.x * GG + cd.y + cd.z * NXX + cd.w;
        map[g] = i;
    }
}

// Kernel 3: gather. Thread = 4 consecutive cells x 16 channels (grid.y slice).
// Per thread: 1 int4 map read, 16 independent float4 loads, 16 float4 nt
// stores -- few long-latency ops per wave, 4x the waves of the previous
// version for memory-level parallelism.
__global__ void __launch_bounds__(256) k_gather(const float* __restrict__ pf,
                                                const int* __restrict__ map,
                                                float* __restrict__ out) {
    int t = blockIdx.x * blockDim.x + threadIdx.x;   // cell-quad id
    const int nGroups = (BB * GG) / 4;               // 214272 = 837*256 exactly
    if (t >= nGroups) return;

    int cellBase = t * 4;
    int b = cellBase / GG;                           // G%4==0: quad never crosses batch
    int cellInB = cellBase - b * GG;

    int4 pids = ((const int4*)map)[t];
    const v4f* pf4 = (const v4f*)pf;                 // pf rows: 64 floats = 16 vec4

    bool v0 = pids.x >= 0, v1 = pids.y >= 0, v2 = pids.z >= 0, v3 = pids.w >= 0;
    int i0 = (v0 ? pids.x : 0) * 16;
    int i1 = (v1 ? pids.y : 0) * 16;
    int i2 = (v2 ? pids.z : 0) * 16;
    int i3 = (v3 ? pids.w : 0) * 16;

    const v4f zero = (v4f)(0.f);
    int qBase = blockIdx.y * 4;                      // this slice: q = qBase..qBase+3
    float* outBase = out + (size_t)(b * CC) * GG + cellInB;

    // Issue all 16 loads up front (independent, unconditional -> pipelined).
    v4f r[4][4];
    #pragma unroll
    for (int j = 0; j < 4; ++j) {
        r[j][0] = pf4[i0 + qBase + j];
        r[j][1] = pf4[i1 + qBase + j];
        r[j][2] = pf4[i2 + qBase + j];
        r[j][3] = pf4[i3 + qBase + j];
    }

    #pragma unroll
    for (int j = 0; j < 4; ++j) {
        v4f r0 = v0 ? r[j][0] : zero;
        v4f r1 = v1 ? r[j][1] : zero;
        v4f r2 = v2 ? r[j][2] : zero;
        v4f r3 = v3 ? r[j][3] : zero;

        int c0 = (qBase + j) * 4;                    // first of 4 channels
        v4f w0 = (v4f){r0.x, r1.x, r2.x, r3.x};
        v4f w1 = (v4f){r0.y, r1.y, r2.y, r3.y};
        v4f w2 = (v4f){r0.z, r1.z, r2.z, r3.z};
        v4f w3 = (v4f){r0.w, r1.w, r2.w, r3.w};

        __builtin_nontemporal_store(w0, (v4f*)(outBase + (size_t)(c0 + 0) * GG));
        __builtin_nontemporal_store(w1, (v4f*)(outBase + (size_t)(c0 + 1) * GG));
        __builtin_nontemporal_store(w2, (v4f*)(outBase + (size_t)(c0 + 2) * GG));
        __builtin_nontemporal_store(w3, (v4f*)(outBase + (size_t)(c0 + 3) * GG));
    }
}

extern "C" void kernel_launch(void* const* d_in, const int* in_sizes, int n_in,
                              void* d_out, int out_size, void* d_ws, size_t ws_size,
                              hipStream_t stream) {
    const float* pf     = (const float*)d_in[0];     // [80000, 64] f32
    const int*   coords = (const int*)d_in[7];       // [80000, 4] i32 (b,z,y,x)
    float*       out    = (float*)d_out;             // [B, C, NY, NX] f32
    int*         map    = (int*)d_ws;                // [B*G] i32 cell->pillar (3.43 MB)

    const int n4 = (BB * GG) / 4;                    // 214272
    k_init_map<<<dim3((n4 + 255) / 256), dim3(256), 0, stream>>>(map);
    k_scatter_ids<<<dim3((PP + 255) / 256), dim3(256), 0, stream>>>(coords, map);

    const int nGroups = (BB * GG) / 4;               // 214272 = 837 * 256 exactly
    dim3 grid((nGroups + 255) / 256, 4);             // 837 x 4 blocks, 16 ch each
    k_gather<<<grid, dim3(256), 0, stream>>>(pf, map, out);
}